// Round 1
// baseline (179.490 us; speedup 1.0000x reference)
//
#include <hip/hip_runtime.h>

#define DEV __device__ __forceinline__

typedef __attribute__((ext_vector_type(4))) float f32x4;
typedef __attribute__((ext_vector_type(8))) short s16x8;

constexpr int B_ = 4, N_ = 4096, D_ = 1024;

DEV float elu1f(float x) { return x > 0.f ? x + 1.f : __expf(x); }
DEV unsigned short f2bf(float x) {            // RNE fp32 -> bf16
  unsigned u = __float_as_uint(x);
  return (unsigned short)((u + 0x7fffu + ((u >> 16) & 1u)) >> 16);
}
DEV float bf2f(unsigned short h) { return __uint_as_float(((unsigned)h) << 16); }

// ---------------- prep q: elu+1 -> bf16, linear ----------------
__global__ __launch_bounds__(256) void k_prep_q(const float* __restrict__ src,
                                                unsigned short* __restrict__ dst) {
  int n = B_ * N_ * D_ / 4;
  int stride = gridDim.x * blockDim.x;
  for (int i = blockIdx.x * blockDim.x + threadIdx.x; i < n; i += stride) {
    f32x4 x = ((const f32x4*)src)[i];
    unsigned long long r =
        (unsigned long long)((unsigned)f2bf(elu1f(x[0])) | ((unsigned)f2bf(elu1f(x[1])) << 16)) |
        ((unsigned long long)((unsigned)f2bf(elu1f(x[2])) | ((unsigned)f2bf(elu1f(x[3])) << 16)) << 32);
    ((unsigned long long*)dst)[i] = r;
  }
}

// ---------------- prep k,v: elu(k)+1, transpose to [D][N] bf16; fused ksum partials ----------------
// v2: LDS holds DWORDS = packed pairs of consecutive-n bf16, already transposed: T_dw[d][n/2].
//     Write side: ds_write_b64 (pair of n-pair dwords). Read side: ds_read_b128. No scalar u16 ops.
// grid = z(2) * b(4) * nb(32) * db(16) = 4096 blocks; tile 128 n x 64 d
__global__ __launch_bounds__(256) void k_prep_tr(const float* __restrict__ K, const float* __restrict__ V,
                                                 unsigned short* __restrict__ kT, unsigned short* __restrict__ vT,
                                                 float* __restrict__ kspart) {
  __shared__ unsigned T[64 * 68];              // [d][68] dwords: 64 n-pair dwords + 4 pad (row 272B)
  int bid = blockIdx.x;
  int z = bid >> 11;
  int r = bid & 2047;
  int b = r >> 9, nb = (r >> 4) & 31, db = r & 15;
  const float* src = (z ? V : K) + ((size_t)b * N_ + nb * 128) * D_ + db * 64;
  unsigned short* dst = (z ? vT : kT) + ((size_t)b * D_ + db * 64) * N_ + nb * 128;
  int t = threadIdx.x;
  // phase 1: load 4 consecutive n rows x 4 d cols, pack pairs-along-n, b64 write (x2 halves)
  int n0 = (t >> 4) * 4;                       // 0..60
  int dc = (t & 15) * 4;                       // 0..60 -> wave reads 256B/row
  #pragma unroll
  for (int h = 0; h < 2; ++h) {
    const float* s0 = src + (size_t)(n0 + 64 * h) * D_ + dc;
    f32x4 x0 = *(const f32x4*)(s0);
    f32x4 x1 = *(const f32x4*)(s0 + D_);
    f32x4 x2 = *(const f32x4*)(s0 + 2 * D_);
    f32x4 x3 = *(const f32x4*)(s0 + 3 * D_);
    if (z == 0) {
      #pragma unroll
      for (int j = 0; j < 4; ++j) { x0[j] = elu1f(x0[j]); x1[j] = elu1f(x1[j]);
                                    x2[j] = elu1f(x2[j]); x3[j] = elu1f(x3[j]); }
    }
    #pragma unroll
    for (int j = 0; j < 4; ++j) {
      unsigned lo = (unsigned)f2bf(x0[j]) | ((unsigned)f2bf(x1[j]) << 16);
      unsigned hi = (unsigned)f2bf(x2[j]) | ((unsigned)f2bf(x3[j]) << 16);
      *(unsigned long long*)&T[(dc + j) * 68 + n0 / 2 + 32 * h] =
          (unsigned long long)lo | ((unsigned long long)hi << 32);
    }
  }
  __syncthreads();
  // phase 2: each thread owns row d, 32 consecutive n as 4x ds_read_b128 -> 4x 16B stores
  int d = t >> 2, cc = t & 3;
  float s = 0.f;
  #pragma unroll
  for (int m = 0; m < 4; ++m) {
    s16x8 w = *(const s16x8*)&T[d * 68 + cc * 16 + m * 4];
    *(s16x8*)(dst + (size_t)d * N_ + cc * 32 + m * 8) = w;
    if (z == 0) {
      #pragma unroll
      for (int j = 0; j < 8; ++j) s += bf2f((unsigned short)w[j]);
    }
  }
  if (z == 0) {                                 // fused ksum partial over this block's 128 n
    s += __shfl_xor(s, 1, 64);
    s += __shfl_xor(s, 2, 64);
    if (cc == 0) kspart[((size_t)b * 32 + nb) * D_ + db * 64 + d] = s;
  }
}

// ---------------- ksum2: reduce 32 partials ----------------
__global__ __launch_bounds__(256) void k_ksum2(const float* __restrict__ kspart, float* __restrict__ ksum) {
  int idx = blockIdx.x * 256 + threadIdx.x;    // 4096 = b*1024 + d
  int b = idx >> 10, d = idx & 1023;
  float a = 0.f;
  #pragma unroll 8
  for (int s = 0; s < 32; ++s) a += kspart[((size_t)b * 32 + s) * D_ + d];
  ksum[idx] = a;
}

// ---------------- denom[b,n] = sum_d q'_bf16 * ksum ----------------
__global__ __launch_bounds__(256) void k_denom(const unsigned short* __restrict__ qp,
                                               const float* __restrict__ ksum, float* __restrict__ den) {
  int wid = threadIdx.x >> 6, lane = threadIdx.x & 63;
  int row = blockIdx.x * 4 + wid;              // [0, B*N)
  int b = row >> 12;
  const unsigned short* qr = qp + (size_t)row * D_ + lane * 16;
  const float* ks = ksum + b * D_ + lane * 16;
  s16x8 h0 = *(const s16x8*)qr;
  s16x8 h1 = *(const s16x8*)(qr + 8);
  float acc = 0.f;
  #pragma unroll
  for (int j = 0; j < 8; ++j) acc += bf2f((unsigned short)h0[j]) * ks[j];
  #pragma unroll
  for (int j = 0; j < 8; ++j) acc += bf2f((unsigned short)h1[j]) * ks[8 + j];
  #pragma unroll
  for (int o = 32; o; o >>= 1) acc += __shfl_down(acc, o, 64);
  if (!lane) den[row] = acc;
}

// ---------------- shared GEMM machinery: 128x128 tile, BK=64, glds + XOR swizzle ----------------
DEV void stage8(const unsigned short* __restrict__ A, const unsigned short* __restrict__ Bp,
                long sA, long sB, unsigned short* LA, unsigned short* LB, int t, int kofs) {
  #pragma unroll
  for (int j = 0; j < 4; ++j) {
    int q = j * 256 + t;
    int r = q >> 3;
    int c = (q & 7) ^ (r & 7);
    const unsigned short* g = A + (size_t)r * sA + kofs + c * 8;
    unsigned short* l = LA + (q & ~63) * 8;    // wave-uniform base; HW adds lane*16
    __builtin_amdgcn_global_load_lds((const __attribute__((address_space(1))) unsigned int*)(const void*)g,
                                     (__attribute__((address_space(3))) unsigned int*)(void*)l, 16, 0, 0);
  }
  #pragma unroll
  for (int j = 0; j < 4; ++j) {
    int q = j * 256 + t;
    int r = q >> 3;
    int c = (q & 7) ^ (r & 7);
    const unsigned short* g = Bp + (size_t)r * sB + kofs + c * 8;
    unsigned short* l = LB + (q & ~63) * 8;
    __builtin_amdgcn_global_load_lds((const __attribute__((address_space(1))) unsigned int*)(const void*)g,
                                     (__attribute__((address_space(3))) unsigned int*)(void*)l, 16, 0, 0);
  }
}

DEV void mac128(const unsigned short* LA, const unsigned short* LB, int lane, int wm, int wn,
                f32x4 (&acc)[4][4]) {
  int rr = lane & 15, cq = lane >> 4;
  #pragma unroll
  for (int ks = 0; ks < 2; ++ks) {
    s16x8 af[4], bf[4];
    #pragma unroll
    for (int m = 0; m < 4; ++m) {
      int row = wm * 64 + m * 16 + rr;
      af[m] = *(const s16x8*)&LA[row * 64 + ((ks * 4 + cq) ^ (rr & 7)) * 8];
    }
    #pragma unroll
    for (int n = 0; n < 4; ++n) {
      int row = wn * 64 + n * 16 + rr;
      bf[n] = *(const s16x8*)&LB[row * 64 + ((ks * 4 + cq) ^ (rr & 7)) * 8];
    }
    #pragma unroll
    for (int m = 0; m < 4; ++m)
      #pragma unroll
      for (int n = 0; n < 4; ++n)
        acc[m][n] = __builtin_amdgcn_mfma_f32_16x16x32_bf16(af[m], bf[n], acc[m][n], 0, 0, 0);
  }
}

// ---------------- GEMM1: part[kc,b,d,e] = sum_{n in kc-half} k'T[d,n] vT[e,n], fp32 ----------------
__global__ __launch_bounds__(256, 2) void k_gemm1(const unsigned short* __restrict__ kT,
                                                  const unsigned short* __restrict__ vT,
                                                  float* __restrict__ part) {
  __shared__ unsigned short LA[2][8192], LB[2][8192];
  int bid = blockIdx.x;
  int b = (bid & 7) >> 1, dh = bid & 1, sg = bid >> 3;
  int kc = sg & 1, dl = (sg >> 1) & 3, e = sg >> 3;
  int d0 = (dh * 4 + dl) * 128, e0 = e * 128;
  const unsigned short* A  = kT + ((size_t)b * D_ + d0) * N_ + kc * 2048;
  const unsigned short* Bp = vT + ((size_t)b * D_ + e0) * N_ + kc * 2048;
  int t = threadIdx.x, lane = t & 63, wid = t >> 6, wm = wid >> 1, wn = wid & 1;
  f32x4 acc[4][4] = {};
  stage8(A, Bp, N_, N_, LA[0], LB[0], t, 0);
  asm volatile("s_waitcnt vmcnt(0)" ::: "memory");
  __syncthreads();
  int cur = 0;
  for (int it = 0; it < 32; ++it) {
    if (it < 31) stage8(A, Bp, N_, N_, LA[cur ^ 1], LB[cur ^ 1], t, (it + 1) * 64);
    mac128(LA[cur], LB[cur], lane, wm, wn, acc);
    asm volatile("s_waitcnt vmcnt(0)" ::: "memory");
    __syncthreads();
    cur ^= 1;
  }
  float* P = part + ((size_t)(kc * 4 + b) << 20) + (size_t)d0 * D_ + e0;
  int rq = (lane >> 4) * 4, cc = lane & 15;
  #pragma unroll
  for (int m = 0; m < 4; ++m)
    #pragma unroll
    for (int r = 0; r < 4; ++r) {
      int row = wm * 64 + m * 16 + rq + r;
      #pragma unroll
      for (int n = 0; n < 4; ++n)
        P[(size_t)row * D_ + wn * 64 + n * 16 + cc] = acc[m][n][r];
    }
}

// ---------------- reduce: kvT[b,e,d] = bf16(part0+part1), transposed via LDS ----------------
// v2: dword-pair LDS transpose (T_dw[e][d/2]); b64 writes, b128 reads, no scalar u16.
__global__ __launch_bounds__(256) void k_reduce(const float* __restrict__ part,
                                                unsigned short* __restrict__ kvT) {
  __shared__ unsigned T[64 * 36];              // [e][36] dwords: 32 d-pair dwords + 4 pad
  int bid = blockIdx.x;                        // b(4) x eb(16) x db(16)
  int b = bid >> 8, eb = (bid >> 4) & 15, db = bid & 15;
  const float* p0 = part + ((size_t)b << 20) + (size_t)(db * 64) * D_ + eb * 64;
  const float* p1 = p0 + ((size_t)4 << 20);
  int t = threadIdx.x;
  int d0 = (t >> 4) * 4, ec = (t & 15) * 4;    // wave reads 256B/row
  f32x4 a0 = *(const f32x4*)(p0 + (size_t)d0 * D_ + ec)       + *(const f32x4*)(p1 + (size_t)d0 * D_ + ec);
  f32x4 a1 = *(const f32x4*)(p0 + (size_t)(d0 + 1) * D_ + ec) + *(const f32x4*)(p1 + (size_t)(d0 + 1) * D_ + ec);
  f32x4 a2 = *(const f32x4*)(p0 + (size_t)(d0 + 2) * D_ + ec) + *(const f32x4*)(p1 + (size_t)(d0 + 2) * D_ + ec);
  f32x4 a3 = *(const f32x4*)(p0 + (size_t)(d0 + 3) * D_ + ec) + *(const f32x4*)(p1 + (size_t)(d0 + 3) * D_ + ec);
  #pragma unroll
  for (int j = 0; j < 4; ++j) {
    unsigned lo = (unsigned)f2bf(a0[j]) | ((unsigned)f2bf(a1[j]) << 16);
    unsigned hi = (unsigned)f2bf(a2[j]) | ((unsigned)f2bf(a3[j]) << 16);
    *(unsigned long long*)&T[(ec + j) * 36 + d0 / 2] =
        (unsigned long long)lo | ((unsigned long long)hi << 32);
  }
  __syncthreads();
  int e = t >> 2, cc = t & 3;
  unsigned short* dstb = kvT + ((size_t)b * D_ + eb * 64 + e) * D_ + db * 64;
  #pragma unroll
  for (int m = 0; m < 2; ++m) {
    s16x8 w = *(const s16x8*)&T[e * 36 + cc * 8 + m * 4];
    *(s16x8*)(dstb + cc * 16 + m * 8) = w;
  }
}

// ---------------- GEMM2: out[b,n,e] = (sum_d q'[n,d] kvT[e,d]) / (den+eps) ----------------
__global__ __launch_bounds__(256, 2) void k_gemm2(const unsigned short* __restrict__ qp,
                                                  const unsigned short* __restrict__ kvT,
                                                  const float* __restrict__ den,
                                                  float* __restrict__ out) {
  __shared__ unsigned short LA[2][8192], LB[2][8192];
  int bid = blockIdx.x;
  int b = (bid & 7) >> 1, mh = bid & 1, sg = bid >> 3;
  int ml = sg & 15, e = sg >> 4;
  int m0 = (mh * 16 + ml) * 128, e0 = e * 128;
  const unsigned short* A  = qp  + ((size_t)b * N_ + m0) * D_;
  const unsigned short* Bp = kvT + ((size_t)b * D_ + e0) * D_;
  int t = threadIdx.x, lane = t & 63, wid = t >> 6, wm = wid >> 1, wn = wid & 1;
  f32x4 acc[4][4] = {};
  stage8(A, Bp, D_, D_, LA[0], LB[0], t, 0);
  asm volatile("s_waitcnt vmcnt(0)" ::: "memory");
  __syncthreads();
  int cur = 0;
  for (int it = 0; it < 16; ++it) {
    if (it < 15) stage8(A, Bp, D_, D_, LA[cur ^ 1], LB[cur ^ 1], t, (it + 1) * 64);
    mac128(LA[cur], LB[cur], lane, wm, wn, acc);
    asm volatile("s_waitcnt vmcnt(0)" ::: "memory");
    __syncthreads();
    cur ^= 1;
  }
  const float* dn = den + b * N_ + m0;
  float* ob = out + ((size_t)b * N_ + m0) * D_ + e0;
  int rq = (lane >> 4) * 4, cc = lane & 15;
  #pragma unroll
  for (int m = 0; m < 4; ++m)
    #pragma unroll
    for (int r = 0; r < 4; ++r) {
      int row = wm * 64 + m * 16 + rq + r;
      float inv = 1.f / (dn[row] + 1e-6f);
      #pragma unroll
      for (int n = 0; n < 4; ++n)
        ob[(size_t)row * D_ + wn * 64 + n * 16 + cc] = acc[m][n][r] * inv;
    }
}

extern "C" void kernel_launch(void* const* d_in, const int* in_sizes, int n_in,
                              void* d_out, int out_size, void* d_ws, size_t ws_size,
                              hipStream_t stream) {
  const float* q = (const float*)d_in[0];
  const float* k = (const float*)d_in[1];
  const float* v = (const float*)d_in[2];
  float* outF = (float*)d_out;
  char* ws = (char*)d_ws;

  // ws: qp 32MB | kT 32MB | vT 32MB | kvT 8MB | ksum 16KB | den 64KB  (= 104.1MB)
  unsigned short* qp  = (unsigned short*)ws;
  unsigned short* kT  = (unsigned short*)(ws + ((size_t)32 << 20));
  unsigned short* vT  = (unsigned short*)(ws + ((size_t)64 << 20));
  unsigned short* kvT = (unsigned short*)(ws + ((size_t)96 << 20));
  float* ksum = (float*)(ws + ((size_t)104 << 20));
  float* den  = (float*)(ws + ((size_t)104 << 20) + 16384);
  // d_out doubles as scratch (fully overwritten by k_gemm2 afterwards):
  float* part   = outF;                 // 2 x 16MB fp32 kv partials
  float* kspart = outF + (8 << 20);     // 512KB ksum partials at +32MB

  k_prep_q <<<1024, 256, 0, stream>>>(q, qp);
  k_prep_tr<<<4096, 256, 0, stream>>>(k, v, kT, vT, kspart);
  k_ksum2  <<<16, 256, 0, stream>>>(kspart, ksum);
  k_gemm1  <<<512, 256, 0, stream>>>(kT, vT, part);
  k_reduce <<<1024, 256, 0, stream>>>(part, kvT);
  k_denom  <<<4096, 256, 0, stream>>>(qp, ksum, den);
  k_gemm2  <<<1024, 256, 0, stream>>>(qp, kvT, den, outF);
}

// Round 2
// 179.363 us; speedup vs baseline: 1.0007x; 1.0007x over previous
//
#include <hip/hip_runtime.h>

#define DEV __device__ __forceinline__

typedef __attribute__((ext_vector_type(4))) float f32x4;
typedef __attribute__((ext_vector_type(8))) short s16x8;
typedef __attribute__((ext_vector_type(4))) unsigned u32x4;

constexpr int B_ = 4, N_ = 4096, D_ = 1024;

DEV float elu1f(float x) { return x > 0.f ? x + 1.f : __expf(x); }
DEV unsigned short f2bf(float x) {            // RNE fp32 -> bf16
  unsigned u = __float_as_uint(x);
  return (unsigned short)((u + 0x7fffu + ((u >> 16) & 1u)) >> 16);
}
DEV float bf2f(unsigned short h) { return __uint_as_float(((unsigned)h) << 16); }

// ---------------- prep q: elu+1 -> bf16, linear ----------------
__global__ __launch_bounds__(256) void k_prep_q(const float* __restrict__ src,
                                                unsigned short* __restrict__ dst) {
  int n = B_ * N_ * D_ / 4;
  int stride = gridDim.x * blockDim.x;
  for (int i = blockIdx.x * blockDim.x + threadIdx.x; i < n; i += stride) {
    f32x4 x = ((const f32x4*)src)[i];
    unsigned long long r =
        (unsigned long long)((unsigned)f2bf(elu1f(x[0])) | ((unsigned)f2bf(elu1f(x[1])) << 16)) |
        ((unsigned long long)((unsigned)f2bf(elu1f(x[2])) | ((unsigned)f2bf(elu1f(x[3])) << 16)) << 32);
    ((unsigned long long*)dst)[i] = r;
  }
}

// ---------------- prep k,v -> n-blocked panels kT/vT[b][p=n/64][d=1024][64 n] bf16 ----------------
// v3: tile = [16 n][all 1024 d] -> 64 KB FULLY CONTIGUOUS global read (no 4KB stride).
//     LDS: T_dw[d][12] dword rows (16B-aligned b128 ops). Writes 32B/d-row into panel quarter;
//     the 4 quarters of a panel share an XCD (wg&7 grouping) for L2 write merge.
// grid 2048: x=wg&7 (xcd), g=wg>>3: z=g>>7, b=(g>>5)&3, nt = x*32 + (g&31)  (nt = 16-n tile id)
__global__ __launch_bounds__(256) void k_prep_tr(const float* __restrict__ K, const float* __restrict__ V,
                                                 unsigned short* __restrict__ kT, unsigned short* __restrict__ vT,
                                                 float* __restrict__ kspart) {
  __shared__ unsigned T[1024 * 12];            // 48 KB, 3 blocks/CU
  int wg = blockIdx.x;
  int x = wg & 7, g = wg >> 3;
  int z = g >> 7, b = (g >> 5) & 3, nt = x * 32 + (g & 31);
  const float* src = (z ? V : K) + ((size_t)b * N_ + nt * 16) * D_;
  int t = threadIdx.x;
  // phase 1: 16 rows x f32x4 per thread, fully contiguous 1KB/wave-instruction
  f32x4 xr[16];
  #pragma unroll
  for (int u = 0; u < 16; ++u)
    xr[u] = *(const f32x4*)(src + (size_t)u * D_ + 4 * t);
  if (z == 0) {
    #pragma unroll
    for (int u = 0; u < 16; ++u) {
      #pragma unroll
      for (int j = 0; j < 4; ++j) xr[u][j] = elu1f(xr[u][j]);
    }
  }
  // pack n-pairs along n, b128 writes at stride 12 dwords (16B-aligned)
  #pragma unroll
  for (int h = 0; h < 2; ++h) {
    #pragma unroll
    for (int j = 0; j < 4; ++j) {
      u32x4 w;
      #pragma unroll
      for (int c = 0; c < 4; ++c) {
        int u = h * 8 + c * 2;
        w[c] = (unsigned)f2bf(xr[u][j]) | ((unsigned)f2bf(xr[u + 1][j]) << 16);
      }
      *(u32x4*)&T[(4 * t + j) * 12 + h * 4] = w;
    }
  }
  __syncthreads();
  // phase 2: thread owns d = t + 256r; 2x ds_read_b128 -> 2x 16B store into panel quarter
  unsigned short* dstz = z ? vT : kT;
  size_t pbase = (size_t)b * ((size_t)N_ * D_) + (size_t)(nt >> 2) * 65536 + (size_t)(nt & 3) * 16;
  #pragma unroll
  for (int r = 0; r < 4; ++r) {
    int d = t + 256 * r;
    s16x8 w0 = *(const s16x8*)&T[d * 12];
    s16x8 w1 = *(const s16x8*)&T[d * 12 + 4];
    *(s16x8*)(dstz + pbase + (size_t)d * 64) = w0;
    *(s16x8*)(dstz + pbase + (size_t)d * 64 + 8) = w1;
    if (z == 0) {                              // ksum partial over this tile's 16 n
      float s = 0.f;
      #pragma unroll
      for (int j = 0; j < 8; ++j)
        s += bf2f((unsigned short)w0[j]) + bf2f((unsigned short)w1[j]);
      kspart[((size_t)b * 256 + nt) * 1024 + d] = s;
    }
  }
}

// ---------------- ksum2: reduce 256 tile-partials, coalesced tiled reduction ----------------
__global__ __launch_bounds__(256) void k_ksum2(const float* __restrict__ kspart, float* __restrict__ ksum) {
  __shared__ float sh[8][132];
  int bid = blockIdx.x;                        // 32 = b(4) x dblk(8)
  int b = bid >> 3, dblk = bid & 7;
  int t = threadIdx.x;
  int sg = t >> 5, dl = (t & 31) * 4;
  const float* base = kspart + ((size_t)b * 256 + sg) * 1024 + dblk * 128 + dl;
  f32x4 a = {};
  #pragma unroll 8
  for (int it = 0; it < 32; ++it)
    a += *(const f32x4*)(base + (size_t)it * 8 * 1024);
  *(f32x4*)&sh[sg][dl] = a;
  __syncthreads();
  if (t < 128) {
    float r = 0.f;
    #pragma unroll
    for (int s = 0; s < 8; ++s) r += sh[s][t];
    ksum[b * 1024 + dblk * 128 + t] = r;
  }
}

// ---------------- denom[b,n] = sum_d q'_bf16 * ksum ----------------
__global__ __launch_bounds__(256) void k_denom(const unsigned short* __restrict__ qp,
                                               const float* __restrict__ ksum, float* __restrict__ den) {
  int wid = threadIdx.x >> 6, lane = threadIdx.x & 63;
  int row = blockIdx.x * 4 + wid;              // [0, B*N)
  int b = row >> 12;
  const unsigned short* qr = qp + (size_t)row * D_ + lane * 16;
  const float* ks = ksum + b * D_ + lane * 16;
  s16x8 h0 = *(const s16x8*)qr;
  s16x8 h1 = *(const s16x8*)(qr + 8);
  float acc = 0.f;
  #pragma unroll
  for (int j = 0; j < 8; ++j) acc += bf2f((unsigned short)h0[j]) * ks[j];
  #pragma unroll
  for (int j = 0; j < 8; ++j) acc += bf2f((unsigned short)h1[j]) * ks[8 + j];
  #pragma unroll
  for (int o = 32; o; o >>= 1) acc += __shfl_down(acc, o, 64);
  if (!lane) den[row] = acc;
}

// ---------------- shared GEMM machinery: 128x128 tile, BK=64, glds + XOR swizzle ----------------
DEV void stage8(const unsigned short* __restrict__ A, const unsigned short* __restrict__ Bp,
                long sA, long sB, unsigned short* LA, unsigned short* LB, int t, int kofs) {
  #pragma unroll
  for (int j = 0; j < 4; ++j) {
    int q = j * 256 + t;
    int r = q >> 3;
    int c = (q & 7) ^ (r & 7);
    const unsigned short* g = A + (size_t)r * sA + kofs + c * 8;
    unsigned short* l = LA + (q & ~63) * 8;    // wave-uniform base; HW adds lane*16
    __builtin_amdgcn_global_load_lds((const __attribute__((address_space(1))) unsigned int*)(const void*)g,
                                     (__attribute__((address_space(3))) unsigned int*)(void*)l, 16, 0, 0);
  }
  #pragma unroll
  for (int j = 0; j < 4; ++j) {
    int q = j * 256 + t;
    int r = q >> 3;
    int c = (q & 7) ^ (r & 7);
    const unsigned short* g = Bp + (size_t)r * sB + kofs + c * 8;
    unsigned short* l = LB + (q & ~63) * 8;
    __builtin_amdgcn_global_load_lds((const __attribute__((address_space(1))) unsigned int*)(const void*)g,
                                     (__attribute__((address_space(3))) unsigned int*)(void*)l, 16, 0, 0);
  }
}

DEV void mac128(const unsigned short* LA, const unsigned short* LB, int lane, int wm, int wn,
                f32x4 (&acc)[4][4]) {
  int rr = lane & 15, cq = lane >> 4;
  #pragma unroll
  for (int ks = 0; ks < 2; ++ks) {
    s16x8 af[4], bf[4];
    #pragma unroll
    for (int m = 0; m < 4; ++m) {
      int row = wm * 64 + m * 16 + rr;
      af[m] = *(const s16x8*)&LA[row * 64 + ((ks * 4 + cq) ^ (rr & 7)) * 8];
    }
    #pragma unroll
    for (int n = 0; n < 4; ++n) {
      int row = wn * 64 + n * 16 + rr;
      bf[n] = *(const s16x8*)&LB[row * 64 + ((ks * 4 + cq) ^ (rr & 7)) * 8];
    }
    #pragma unroll
    for (int m = 0; m < 4; ++m)
      #pragma unroll
      for (int n = 0; n < 4; ++n)
        acc[m][n] = __builtin_amdgcn_mfma_f32_16x16x32_bf16(af[m], bf[n], acc[m][n], 0, 0, 0);
  }
}

// ---------------- GEMM1: part[kc,b,d,e] = sum_{n in kc-half} k' v, panel layout ----------------
// A row r (=d) of panel p lives at b*N*D + p*65536 + (d0+r)*64; K-step it selects panel kc*32+it.
__global__ __launch_bounds__(256, 2) void k_gemm1(const unsigned short* __restrict__ kT,
                                                  const unsigned short* __restrict__ vT,
                                                  float* __restrict__ part) {
  __shared__ unsigned short LA[2][8192], LB[2][8192];
  int bid = blockIdx.x;
  int b = (bid & 7) >> 1, dh = bid & 1, sg = bid >> 3;
  int kc = sg & 1, dl = (sg >> 1) & 3, e = sg >> 3;
  int d0 = (dh * 4 + dl) * 128, e0 = e * 128;
  const unsigned short* A  = kT + (size_t)b * ((size_t)N_ * D_) + (size_t)(kc * 32) * 65536 + (size_t)d0 * 64;
  const unsigned short* Bp = vT + (size_t)b * ((size_t)N_ * D_) + (size_t)(kc * 32) * 65536 + (size_t)e0 * 64;
  int t = threadIdx.x, lane = t & 63, wid = t >> 6, wm = wid >> 1, wn = wid & 1;
  f32x4 acc[4][4] = {};
  stage8(A, Bp, 64, 64, LA[0], LB[0], t, 0);
  asm volatile("s_waitcnt vmcnt(0)" ::: "memory");
  __syncthreads();
  int cur = 0;
  for (int it = 0; it < 32; ++it) {
    if (it < 31) stage8(A, Bp, 64, 64, LA[cur ^ 1], LB[cur ^ 1], t, (it + 1) * 65536);
    mac128(LA[cur], LB[cur], lane, wm, wn, acc);
    asm volatile("s_waitcnt vmcnt(0)" ::: "memory");
    __syncthreads();
    cur ^= 1;
  }
  float* P = part + ((size_t)(kc * 4 + b) << 20) + (size_t)d0 * D_ + e0;
  int rq = (lane >> 4) * 4, cc = lane & 15;
  #pragma unroll
  for (int m = 0; m < 4; ++m)
    #pragma unroll
    for (int r = 0; r < 4; ++r) {
      int row = wm * 64 + m * 16 + rq + r;
      #pragma unroll
      for (int n = 0; n < 4; ++n)
        P[(size_t)row * D_ + wn * 64 + n * 16 + cc] = acc[m][n][r];
    }
}

// ---------------- reduce: kvT[b,e,d] = bf16(part0+part1), transposed via LDS ----------------
__global__ __launch_bounds__(256) void k_reduce(const float* __restrict__ part,
                                                unsigned short* __restrict__ kvT) {
  __shared__ unsigned T[64 * 36];              // [e][36] dwords: 32 d-pair dwords + 4 pad
  int bid = blockIdx.x;                        // b(4) x eb(16) x db(16)
  int b = bid >> 8, eb = (bid >> 4) & 15, db = bid & 15;
  const float* p0 = part + ((size_t)b << 20) + (size_t)(db * 64) * D_ + eb * 64;
  const float* p1 = p0 + ((size_t)4 << 20);
  int t = threadIdx.x;
  int d0 = (t >> 4) * 4, ec = (t & 15) * 4;    // wave reads 256B/row
  f32x4 a0 = *(const f32x4*)(p0 + (size_t)d0 * D_ + ec)       + *(const f32x4*)(p1 + (size_t)d0 * D_ + ec);
  f32x4 a1 = *(const f32x4*)(p0 + (size_t)(d0 + 1) * D_ + ec) + *(const f32x4*)(p1 + (size_t)(d0 + 1) * D_ + ec);
  f32x4 a2 = *(const f32x4*)(p0 + (size_t)(d0 + 2) * D_ + ec) + *(const f32x4*)(p1 + (size_t)(d0 + 2) * D_ + ec);
  f32x4 a3 = *(const f32x4*)(p0 + (size_t)(d0 + 3) * D_ + ec) + *(const f32x4*)(p1 + (size_t)(d0 + 3) * D_ + ec);
  #pragma unroll
  for (int j = 0; j < 4; ++j) {
    unsigned lo = (unsigned)f2bf(a0[j]) | ((unsigned)f2bf(a1[j]) << 16);
    unsigned hi = (unsigned)f2bf(a2[j]) | ((unsigned)f2bf(a3[j]) << 16);
    *(unsigned long long*)&T[(ec + j) * 36 + d0 / 2] =
        (unsigned long long)lo | ((unsigned long long)hi << 32);
  }
  __syncthreads();
  int e = t >> 2, cc = t & 3;
  unsigned short* dstb = kvT + ((size_t)b * D_ + eb * 64 + e) * D_ + db * 64;
  #pragma unroll
  for (int m = 0; m < 2; ++m) {
    s16x8 w = *(const s16x8*)&T[e * 36 + cc * 8 + m * 4];
    *(s16x8*)(dstb + cc * 16 + m * 8) = w;
  }
}

// ---------------- GEMM2: out[b,n,e] = (sum_d q'[n,d] kvT[e,d]) / (den+eps) ----------------
__global__ __launch_bounds__(256, 2) void k_gemm2(const unsigned short* __restrict__ qp,
                                                  const unsigned short* __restrict__ kvT,
                                                  const float* __restrict__ den,
                                                  float* __restrict__ out) {
  __shared__ unsigned short LA[2][8192], LB[2][8192];
  int bid = blockIdx.x;
  int b = (bid & 7) >> 1, mh = bid & 1, sg = bid >> 3;
  int ml = sg & 15, e = sg >> 4;
  int m0 = (mh * 16 + ml) * 128, e0 = e * 128;
  const unsigned short* A  = qp  + ((size_t)b * N_ + m0) * D_;
  const unsigned short* Bp = kvT + ((size_t)b * D_ + e0) * D_;
  int t = threadIdx.x, lane = t & 63, wid = t >> 6, wm = wid >> 1, wn = wid & 1;
  f32x4 acc[4][4] = {};
  stage8(A, Bp, D_, D_, LA[0], LB[0], t, 0);
  asm volatile("s_waitcnt vmcnt(0)" ::: "memory");
  __syncthreads();
  int cur = 0;
  for (int it = 0; it < 16; ++it) {
    if (it < 15) stage8(A, Bp, D_, D_, LA[cur ^ 1], LB[cur ^ 1], t, (it + 1) * 64);
    mac128(LA[cur], LB[cur], lane, wm, wn, acc);
    asm volatile("s_waitcnt vmcnt(0)" ::: "memory");
    __syncthreads();
    cur ^= 1;
  }
  const float* dn = den + b * N_ + m0;
  float* ob = out + ((size_t)b * N_ + m0) * D_ + e0;
  int rq = (lane >> 4) * 4, cc = lane & 15;
  #pragma unroll
  for (int m = 0; m < 4; ++m)
    #pragma unroll
    for (int r = 0; r < 4; ++r) {
      int row = wm * 64 + m * 16 + rq + r;
      float inv = 1.f / (dn[row] + 1e-6f);
      #pragma unroll
      for (int n = 0; n < 4; ++n)
        ob[(size_t)row * D_ + wn * 64 + n * 16 + cc] = acc[m][n][r] * inv;
    }
}

extern "C" void kernel_launch(void* const* d_in, const int* in_sizes, int n_in,
                              void* d_out, int out_size, void* d_ws, size_t ws_size,
                              hipStream_t stream) {
  const float* q = (const float*)d_in[0];
  const float* k = (const float*)d_in[1];
  const float* v = (const float*)d_in[2];
  float* outF = (float*)d_out;
  char* ws = (char*)d_ws;

  // ws: qp 32MB | kT 32MB | vT 32MB | kvT 8MB | ksum 16KB | den 64KB  (= 104.1MB)
  unsigned short* qp  = (unsigned short*)ws;
  unsigned short* kT  = (unsigned short*)(ws + ((size_t)32 << 20));
  unsigned short* vT  = (unsigned short*)(ws + ((size_t)64 << 20));
  unsigned short* kvT = (unsigned short*)(ws + ((size_t)96 << 20));
  float* ksum = (float*)(ws + ((size_t)104 << 20));
  float* den  = (float*)(ws + ((size_t)104 << 20) + 16384);
  // d_out doubles as scratch (fully overwritten by k_gemm2 afterwards):
  float* part   = outF;                 // 2 x 16MB fp32 kv partials
  float* kspart = outF + (8 << 20);     // 4MB ksum tile-partials at +32MB

  k_prep_q <<<1024, 256, 0, stream>>>(q, qp);
  k_prep_tr<<<2048, 256, 0, stream>>>(k, v, kT, vT, kspart);
  k_ksum2  <<<32, 256, 0, stream>>>(kspart, ksum);
  k_gemm1  <<<512, 256, 0, stream>>>(kT, vT, part);
  k_reduce <<<1024, 256, 0, stream>>>(part, kvT);
  k_denom  <<<4096, 256, 0, stream>>>(qp, ksum, den);
  k_gemm2  <<<1024, 256, 0, stream>>>(qp, kvT, den, outF);
}